// Round 5
// baseline (651.240 us; speedup 1.0000x reference)
//
#include <hip/hip_runtime.h>
#include <hip/hip_bf16.h>

#define N_NODES 50000
#define N_EDGES 150000
#define N_FACES 100000
#define NB 64      // graphs
#define NS 32      // thresholds
#define NT 32      // directions
#define SCALE_C 500.0f
#define DLIN (2.0f / 31.0f)
#define INV_DLIN (31.0f / 2.0f)
#define WIN 0.02f          // TH/SCALE with TH=10: sigmoid tail < 4.6e-5
#define TOTAL (N_NODES + N_EDGES + N_FACES)

__device__ __forceinline__ float sigf(float z) {
    float e = __expf(-z);
    return __builtin_amdgcn_rcpf(1.0f + e);
}

// ---- K1: node heights nh[n][t] = nw[n] * (x[n,:] . v[:,t]) ----------------
__global__ void nh_kernel(const float* __restrict__ x, const float* __restrict__ nw,
                          const float* __restrict__ v, float* __restrict__ nh) {
    int idx = blockIdx.x * blockDim.x + threadIdx.x;
    if (idx >= N_NODES * NT) return;
    int n = idx >> 5, t = idx & 31;
    float w = nw[n];
    float x0 = x[3 * n], x1 = x[3 * n + 1], x2 = x[3 * n + 2];
    nh[idx] = w * (x0 * v[t] + x1 * v[NT + t] + x2 * v[2 * NT + t]);
}

// ---- K2: step-decomposed accumulate into delta basis ----------------------
// delta[g][s][t]: out[g][s][t] = prefix_sum_s(delta). Per (simplex,t):
//   bins with |500(lin_s-h)| < 10 get exact sigmoid deltas; first bin fully
//   above the window gets the step remainder (1 - last_v).
__global__ __launch_bounds__(256) void accum_kernel(
    const float* __restrict__ nh, const int* __restrict__ batch,
    const int* __restrict__ ei, const float* __restrict__ ew,
    const int* __restrict__ fi, const float* __restrict__ fw,
    float* __restrict__ delta)
{
    int t = threadIdx.x & 31;
    int slot = threadIdx.x >> 5;              // 0..7: which simplex slot in block
    int stride = gridDim.x * 8;
    for (int i = blockIdx.x * 8 + slot; i < TOTAL; i += stride) {
        float h, sign;
        int g;
        if (i < N_NODES) {
            g = batch[i];
            h = nh[i * NT + t];
            sign = 1.0f;
        } else if (i < N_NODES + N_EDGES) {
            int e = i - N_NODES;
            int na = ei[e], nb = ei[N_EDGES + e];
            g = batch[na];
            h = fmaxf(nh[na * NT + t], nh[nb * NT + t]) * ew[e];
            sign = -1.0f;
        } else {
            int f = i - N_NODES - N_EDGES;
            int na = fi[f], nb = fi[N_FACES + f], nc = fi[2 * N_FACES + f];
            g = batch[na];
            h = fmaxf(fmaxf(nh[na * NT + t], nh[nb * NT + t]), nh[nc * NT + t]) * fw[f];
            sign = 1.0f;
        }
        int slo_u = (int)ceilf((h - WIN + 1.0f) * INV_DLIN);
        int shi_u = (int)floorf((h + WIN + 1.0f) * INV_DLIN);
        int slo = slo_u < 0 ? 0 : slo_u;
        int shi = shi_u > (NS - 1) ? (NS - 1) : shi_u;
        float prev = 0.0f;
        float* dg = delta + (g * NS) * NT + t;
        for (int s = slo; s <= shi; s++) {
            float vs = sigf(SCALE_C * (-1.0f + s * DLIN - h));
            atomicAdd(dg + s * NT, sign * (vs - prev));
            prev = vs;
        }
        int sstep = shi_u + 1;                // first fully-saturated bin
        if (sstep <= NS - 1) {
            int sc = sstep < 0 ? 0 : sstep;
            atomicAdd(dg + sc * NT, sign * (1.0f - prev));
        }
    }
}

// ---- K3: prefix-sum delta over s -> out -----------------------------------
__global__ void finalize_kernel(const float* __restrict__ delta, float* __restrict__ out) {
    int idx = blockIdx.x * blockDim.x + threadIdx.x;   // 0..NB*NT-1, (g,t)
    if (idx >= NB * NT) return;
    int g = idx >> 5, t = idx & 31;
    const float* dg = delta + (g * NS) * NT + t;
    float* og = out + (g * NS) * NT + t;
    float run = 0.0f;
    for (int s = 0; s < NS; s++) {
        run += dg[s * NT];
        og[s * NT] = run;
    }
}

extern "C" void kernel_launch(void* const* d_in, const int* in_sizes, int n_in,
                              void* d_out, int out_size, void* d_ws, size_t ws_size,
                              hipStream_t stream) {
    const float* x     = (const float*)d_in[0];
    const float* nw    = (const float*)d_in[1];
    const int*   ei    = (const int*)d_in[2];
    const float* ew    = (const float*)d_in[3];
    const int*   fi    = (const int*)d_in[4];
    const float* fw    = (const float*)d_in[5];
    const int*   batch = (const int*)d_in[6];
    const float* v     = (const float*)d_in[7];
    const float* lin   = (const float*)d_in[8];
    (void)lin; (void)in_sizes; (void)n_in; (void)ws_size;
    float* out = (float*)d_out;

    char* ws = (char*)d_ws;
    float* delta = (float*)ws;                                  // NB*NS*NT f32 = 256 KB
    float* nh    = (float*)(ws + (size_t)NB * NS * NT * 4);     // N*T f32 = 6.4 MB

    hipMemsetAsync(delta, 0, (size_t)NB * NS * NT * sizeof(float), stream);

    nh_kernel<<<(N_NODES * NT + 255) / 256, 256, 0, stream>>>(x, nw, v, nh);
    accum_kernel<<<2048, 256, 0, stream>>>(nh, batch, ei, ew, fi, fw, delta);
    finalize_kernel<<<(NB * NT + 255) / 256, 256, 0, stream>>>(delta, out);
}

// Round 6
// 441.227 us; speedup vs baseline: 1.4760x; 1.4760x over previous
//
#include <hip/hip_runtime.h>
#include <hip/hip_bf16.h>

#define N_NODES 50000
#define N_EDGES 150000
#define N_FACES 100000
#define NB 64      // graphs
#define NS 32      // thresholds
#define NT 32      // directions
#define NREP 8     // delta replicas (one per XCD)
#define SCALE_C 500.0f
#define DLIN (2.0f / 31.0f)
#define INV_DLIN (31.0f / 2.0f)
#define WIN 0.02f          // TH/SCALE with TH=10: sigmoid tail < 4.6e-5
#define TOTAL (N_NODES + N_EDGES + N_FACES)
#define DSZ (NB * NS * NT) // 65536 floats per replica

__device__ __forceinline__ float sigf(float z) {
    float e = __expf(-z);
    return __builtin_amdgcn_rcpf(1.0f + e);
}

// ---- K1: node heights nh[n][t] = nw[n] * (x[n,:] . v[:,t]) ----------------
__global__ void nh_kernel(const float* __restrict__ x, const float* __restrict__ nw,
                          const float* __restrict__ v, float* __restrict__ nh) {
    int idx = blockIdx.x * blockDim.x + threadIdx.x;
    if (idx >= N_NODES * NT) return;
    int n = idx >> 5, t = idx & 31;
    float w = nw[n];
    float x0 = x[3 * n], x1 = x[3 * n + 1], x2 = x[3 * n + 2];
    nh[idx] = w * (x0 * v[t] + x1 * v[NT + t] + x2 * v[2 * NT + t]);
}

// ---- K2: step-decomposed accumulate into per-XCD delta replicas -----------
// delta[rep][g][s][t]: out[g][s][t] = prefix_sum_s(sum_rep delta).
// Per (simplex,t): bins with |500(lin_s-h)| < 10 get exact sigmoid deltas;
// first bin fully above the window gets the step remainder (1 - last_v).
// rep = blockIdx.x & 7 keeps atomics XCD-L2-local (round-robin dispatch).
__global__ __launch_bounds__(256) void accum_kernel(
    const float* __restrict__ nh, const int* __restrict__ batch,
    const int* __restrict__ ei, const float* __restrict__ ew,
    const int* __restrict__ fi, const float* __restrict__ fw,
    float* __restrict__ delta)
{
    int t = threadIdx.x & 31;
    int slot = threadIdx.x >> 5;              // 0..7: simplex slot in block
    float* drep = delta + (size_t)(blockIdx.x & (NREP - 1)) * DSZ;
    int stride = gridDim.x * 8;
    for (int i = blockIdx.x * 8 + slot; i < TOTAL; i += stride) {
        float h, sign;
        int g;
        if (i < N_NODES) {
            g = batch[i];
            h = nh[i * NT + t];
            sign = 1.0f;
        } else if (i < N_NODES + N_EDGES) {
            int e = i - N_NODES;
            int na = ei[e], nb = ei[N_EDGES + e];
            g = batch[na];
            h = fmaxf(nh[na * NT + t], nh[nb * NT + t]) * ew[e];
            sign = -1.0f;
        } else {
            int f = i - N_NODES - N_EDGES;
            int na = fi[f], nb = fi[N_FACES + f], nc = fi[2 * N_FACES + f];
            g = batch[na];
            h = fmaxf(fmaxf(nh[na * NT + t], nh[nb * NT + t]), nh[nc * NT + t]) * fw[f];
            sign = 1.0f;
        }
        int slo_u = (int)ceilf((h - WIN + 1.0f) * INV_DLIN);
        int shi_u = (int)floorf((h + WIN + 1.0f) * INV_DLIN);
        int slo = slo_u < 0 ? 0 : slo_u;
        int shi = shi_u > (NS - 1) ? (NS - 1) : shi_u;
        float prev = 0.0f;
        float* dg = drep + (g * NS) * NT + t;
        for (int s = slo; s <= shi; s++) {
            float vs = sigf(SCALE_C * (-1.0f + s * DLIN - h));
            atomicAdd(dg + s * NT, sign * (vs - prev));
            prev = vs;
        }
        int sstep = shi_u + 1;                // first fully-saturated bin
        if (sstep <= NS - 1) {
            int sc = sstep < 0 ? 0 : sstep;
            atomicAdd(dg + sc * NT, sign * (1.0f - prev));
        }
    }
}

// ---- K3: reduce replicas + prefix-sum over s -> out -----------------------
__global__ void finalize_kernel(const float* __restrict__ delta, float* __restrict__ out) {
    int idx = blockIdx.x * blockDim.x + threadIdx.x;   // 0..NB*NT-1, (g,t)
    if (idx >= NB * NT) return;
    int g = idx >> 5, t = idx & 31;
    const float* dg = delta + (g * NS) * NT + t;
    float* og = out + (g * NS) * NT + t;
    float run = 0.0f;
    for (int s = 0; s < NS; s++) {
        float d = 0.0f;
        #pragma unroll
        for (int r = 0; r < NREP; r++) d += dg[(size_t)r * DSZ + s * NT];
        run += d;
        og[s * NT] = run;
    }
}

extern "C" void kernel_launch(void* const* d_in, const int* in_sizes, int n_in,
                              void* d_out, int out_size, void* d_ws, size_t ws_size,
                              hipStream_t stream) {
    const float* x     = (const float*)d_in[0];
    const float* nw    = (const float*)d_in[1];
    const int*   ei    = (const int*)d_in[2];
    const float* ew    = (const float*)d_in[3];
    const int*   fi    = (const int*)d_in[4];
    const float* fw    = (const float*)d_in[5];
    const int*   batch = (const int*)d_in[6];
    const float* v     = (const float*)d_in[7];
    const float* lin   = (const float*)d_in[8];
    (void)lin; (void)in_sizes; (void)n_in; (void)ws_size;
    float* out = (float*)d_out;

    char* ws = (char*)d_ws;
    float* delta = (float*)ws;                                   // NREP*64K f32 = 2 MB
    float* nh    = (float*)(ws + (size_t)NREP * DSZ * 4);        // N*T f32 = 6.4 MB

    hipMemsetAsync(delta, 0, (size_t)NREP * DSZ * sizeof(float), stream);

    nh_kernel<<<(N_NODES * NT + 255) / 256, 256, 0, stream>>>(x, nw, v, nh);
    accum_kernel<<<2048, 256, 0, stream>>>(nh, batch, ei, ew, fi, fw, delta);
    finalize_kernel<<<(NB * NT + 255) / 256, 256, 0, stream>>>(delta, out);
}

// Round 7
// 197.837 us; speedup vs baseline: 3.2918x; 2.2303x over previous
//
#include <hip/hip_runtime.h>
#include <hip/hip_bf16.h>

#define N_NODES 50000
#define N_EDGES 150000
#define N_FACES 100000
#define NB 64      // graphs
#define NS 32      // thresholds
#define NT 32      // directions
#define SCALE_C 500.0f
#define DLIN (2.0f / 31.0f)
#define INV_DLIN (31.0f / 2.0f)
#define WIN 0.02f          // TH/SCALE with TH=10: sigmoid tail < 4.6e-5
#define DSZ (NB * NS * NT) // 65536 floats
#define CH 256             // simplices per accum block
#define WG 4               // LDS window: graphs per block tile

__device__ __forceinline__ float sigf(float z) {
    float e = __expf(-z);
    return __builtin_amdgcn_rcpf(1.0f + e);
}

// ---- K1: node heights nh[n][t] = nw[n] * (x[n,:] . v[:,t]) ----------------
__global__ void nh_kernel(const float* __restrict__ x, const float* __restrict__ nw,
                          const float* __restrict__ v, float* __restrict__ nh) {
    int idx = blockIdx.x * blockDim.x + threadIdx.x;
    if (idx >= N_NODES * NT) return;
    int n = idx >> 5, t = idx & 31;
    float w = nw[n];
    float x0 = x[3 * n], x1 = x[3 * n + 1], x2 = x[3 * n + 2];
    nh[idx] = w * (x0 * v[t] + x1 * v[NT + t] + x2 * v[2 * NT + t]);
}

// ---- K2: graph ids for edges/faces + per-graph histograms -----------------
__global__ void hist_kernel(const int* __restrict__ ei, const int* __restrict__ fi,
                            const int* __restrict__ batch,
                            int* __restrict__ ge, int* __restrict__ gf,
                            int* __restrict__ hist_e, int* __restrict__ hist_f) {
    __shared__ int he[NB], hf[NB];
    if (threadIdx.x < NB) { he[threadIdx.x] = 0; hf[threadIdx.x] = 0; }
    __syncthreads();
    int stride = gridDim.x * blockDim.x;
    for (int i = blockIdx.x * blockDim.x + threadIdx.x; i < N_EDGES; i += stride) {
        int g = batch[ei[i]];
        ge[i] = g;
        atomicAdd(&he[g], 1);
    }
    for (int i = blockIdx.x * blockDim.x + threadIdx.x; i < N_FACES; i += stride) {
        int g = batch[fi[i]];
        gf[i] = g;
        atomicAdd(&hf[g], 1);
    }
    __syncthreads();
    if (threadIdx.x < NB) {
        if (he[threadIdx.x]) atomicAdd(&hist_e[threadIdx.x], he[threadIdx.x]);
        if (hf[threadIdx.x]) atomicAdd(&hist_f[threadIdx.x], hf[threadIdx.x]);
    }
}

// ---- K3: parallel exclusive scan (64 bins x 2 lists) ----------------------
__global__ void scan_kernel(const int* __restrict__ hist_e, const int* __restrict__ hist_f,
                            int* __restrict__ cur_e, int* __restrict__ cur_f) {
    __shared__ int sh[128];
    int tid = threadIdx.x;                 // 128 threads
    sh[tid] = (tid < 64) ? hist_e[tid] : hist_f[tid - 64];
    __syncthreads();
    int which = tid >> 6, lane = tid & 63;
    int s = 0;
    for (int g = 0; g < lane; g++) s += sh[which * 64 + g];
    if (which == 0) cur_e[lane] = s; else cur_f[lane] = s;
}

// ---- K4: two-level counting-sort scatter ----------------------------------
__global__ void scatter_kernel(const int* __restrict__ garr, int M,
                               int* __restrict__ cursors,
                               int* __restrict__ perm, int* __restrict__ gs) {
    __shared__ int cnt[NB], base[NB];
    int c0 = blockIdx.x * 1024;
    if (threadIdx.x < NB) cnt[threadIdx.x] = 0;
    __syncthreads();
    int gv[4], ev[4], n = 0;
    #pragma unroll
    for (int k = 0; k < 4; k++) {
        int i = c0 + k * 256 + threadIdx.x;
        if (i < M) { ev[n] = i; gv[n] = garr[i]; atomicAdd(&cnt[gv[n]], 1); n++; }
    }
    __syncthreads();
    if (threadIdx.x < NB) {
        base[threadIdx.x] = atomicAdd(&cursors[threadIdx.x], cnt[threadIdx.x]);
        cnt[threadIdx.x] = 0;
    }
    __syncthreads();
    for (int k = 0; k < n; k++) {
        int pos = base[gv[k]] + atomicAdd(&cnt[gv[k]], 1);
        perm[pos] = ev[k];
        gs[pos] = gv[k];
    }
}

// ---- K5: delta-basis accumulate, LDS-windowed, sorted chunks --------------
// Each block: CH graph-sorted simplices of one type; LDS tile covers graphs
// [g0, g0+WG). Deltas go to LDS atomics (bank==lane, conflict-free); one
// coalesced global-atomic flush of nonzero cells at the end.
__global__ __launch_bounds__(256) void accum_kernel(
    const float* __restrict__ nh, const int* __restrict__ batch,
    const int* __restrict__ ei, const float* __restrict__ ew,
    const int* __restrict__ perm_e, const int* __restrict__ gs_e,
    const int* __restrict__ fi, const float* __restrict__ fw,
    const int* __restrict__ perm_f, const int* __restrict__ gs_f,
    float* __restrict__ delta, int nbn, int nbe)
{
    __shared__ float tile[WG * NS * NT];   // 16 KB
    int t = threadIdx.x & 31, slot = threadIdx.x >> 5;
    int bid = blockIdx.x;
    int type, i0, i1;
    float sign;
    if (bid < nbn) {
        type = 0; i0 = bid * CH; i1 = min(i0 + CH, N_NODES); sign = 1.0f;
    } else if (bid < nbn + nbe) {
        type = 1; int b = bid - nbn; i0 = b * CH; i1 = min(i0 + CH, N_EDGES); sign = -1.0f;
    } else {
        type = 2; int b = bid - nbn - nbe; i0 = b * CH; i1 = min(i0 + CH, N_FACES); sign = 1.0f;
    }
    int g0 = (type == 0) ? batch[i0] : (type == 1 ? gs_e[i0] : gs_f[i0]);

    for (int k = threadIdx.x; k < WG * NS * NT; k += 256) tile[k] = 0.0f;
    __syncthreads();

    #define EMIT(S, VAL) do { \
        int _o = (S) * NT + t; \
        if (wi < WG) atomicAdd(&tile[wi * (NS * NT) + _o], (VAL)); \
        else atomicAdd(&delta[g * (NS * NT) + _o], sign * (VAL)); } while (0)

    for (int i = i0 + slot; i < i1; i += 8) {
        float h;
        int g;
        if (type == 0) {
            g = batch[i];
            h = nh[i * NT + t];
        } else if (type == 1) {
            g = gs_e[i];
            int e = perm_e[i];
            int na = ei[e], nb = ei[N_EDGES + e];
            h = fmaxf(nh[na * NT + t], nh[nb * NT + t]) * ew[e];
        } else {
            g = gs_f[i];
            int f = perm_f[i];
            int na = fi[f], nb = fi[N_FACES + f], nc = fi[2 * N_FACES + f];
            h = fmaxf(fmaxf(nh[na * NT + t], nh[nb * NT + t]), nh[nc * NT + t]) * fw[f];
        }
        int wi = g - g0;
        int slo_u = (int)ceilf((h - WIN + 1.0f) * INV_DLIN);
        int shi_u = (int)floorf((h + WIN + 1.0f) * INV_DLIN);
        int slo = slo_u < 0 ? 0 : slo_u;
        int shi = shi_u > (NS - 1) ? (NS - 1) : shi_u;
        float prev = 0.0f;
        for (int s = slo; s <= shi; s++) {
            float vs = sigf(SCALE_C * (-1.0f + s * DLIN - h));
            EMIT(s, vs - prev);
            prev = vs;
        }
        int sstep = shi_u + 1;
        if (sstep <= NS - 1) {
            int sc = sstep < 0 ? 0 : sstep;
            EMIT(sc, 1.0f - prev);
        }
    }
    #undef EMIT

    __syncthreads();
    // flush nonzero cells (sign applied here for LDS-path entries)
    for (int k = threadIdx.x; k < WG * NS * NT; k += 256) {
        float vv = tile[k];
        if (vv != 0.0f) {
            int wi = k >> 10, cell = k & (NS * NT - 1);
            int g = g0 + wi;
            if (g < NB) atomicAdd(&delta[g * (NS * NT) + cell], sign * vv);
        }
    }
}

// ---- K6: prefix-sum delta over s -> out -----------------------------------
__global__ void finalize_kernel(const float* __restrict__ delta, float* __restrict__ out) {
    int idx = blockIdx.x * blockDim.x + threadIdx.x;   // 0..NB*NT-1, (g,t)
    if (idx >= NB * NT) return;
    int g = idx >> 5, t = idx & 31;
    const float* dg = delta + (g * NS) * NT + t;
    float* og = out + (g * NS) * NT + t;
    float run = 0.0f;
    for (int s = 0; s < NS; s++) {
        run += dg[s * NT];
        og[s * NT] = run;
    }
}

extern "C" void kernel_launch(void* const* d_in, const int* in_sizes, int n_in,
                              void* d_out, int out_size, void* d_ws, size_t ws_size,
                              hipStream_t stream) {
    const float* x     = (const float*)d_in[0];
    const float* nw    = (const float*)d_in[1];
    const int*   ei    = (const int*)d_in[2];
    const float* ew    = (const float*)d_in[3];
    const int*   fi    = (const int*)d_in[4];
    const float* fw    = (const float*)d_in[5];
    const int*   batch = (const int*)d_in[6];
    const float* v     = (const float*)d_in[7];
    const float* lin   = (const float*)d_in[8];
    (void)lin; (void)in_sizes; (void)n_in; (void)ws_size;
    float* out = (float*)d_out;

    char* ws = (char*)d_ws;
    float* delta  = (float*)ws;                         // 256 KB
    int*   hist_e = (int*)(ws + DSZ * 4);               // 64
    int*   hist_f = hist_e + 64;
    int*   cur_e  = hist_e + 128;
    int*   cur_f  = hist_e + 192;
    float* nh     = (float*)(ws + DSZ * 4 + 1024);      // 6.4 MB
    int*   ge     = (int*)((char*)nh + (size_t)N_NODES * NT * 4);
    int*   gf     = ge + N_EDGES;
    int*   perm_e = gf + N_FACES;
    int*   gs_e   = perm_e + N_EDGES;
    int*   perm_f = gs_e + N_EDGES;
    int*   gs_f   = perm_f + N_FACES;

    // one memset covers delta + hist/cursors
    hipMemsetAsync(delta, 0, DSZ * 4 + 1024, stream);

    nh_kernel<<<(N_NODES * NT + 255) / 256, 256, 0, stream>>>(x, nw, v, nh);
    hist_kernel<<<512, 256, 0, stream>>>(ei, fi, batch, ge, gf, hist_e, hist_f);
    scan_kernel<<<1, 128, 0, stream>>>(hist_e, hist_f, cur_e, cur_f);
    scatter_kernel<<<(N_EDGES + 1023) / 1024, 256, 0, stream>>>(ge, N_EDGES, cur_e, perm_e, gs_e);
    scatter_kernel<<<(N_FACES + 1023) / 1024, 256, 0, stream>>>(gf, N_FACES, cur_f, perm_f, gs_f);

    int nbn = (N_NODES + CH - 1) / CH;
    int nbe = (N_EDGES + CH - 1) / CH;
    int nbf = (N_FACES + CH - 1) / CH;
    accum_kernel<<<nbn + nbe + nbf, 256, 0, stream>>>(
        nh, batch, ei, ew, perm_e, gs_e, fi, fw, perm_f, gs_f, delta, nbn, nbe);
    finalize_kernel<<<(NB * NT + 255) / 256, 256, 0, stream>>>(delta, out);
}

// Round 8
// 189.894 us; speedup vs baseline: 3.4295x; 1.0418x over previous
//
#include <hip/hip_runtime.h>
#include <hip/hip_bf16.h>

#define N_NODES 50000
#define N_EDGES 150000
#define N_FACES 100000
#define NB 64      // graphs
#define NS 32      // thresholds
#define NT 32      // directions
#define SCALE_C 500.0f
#define DLIN (2.0f / 31.0f)
#define INV_DLIN (31.0f / 2.0f)
#define WIN 0.02f          // TH/SCALE with TH=10: sigmoid tail < 4.6e-5
#define DSZ (NB * NS * NT) // 65536 floats
#define CH 128             // simplices per accum block
#define WG 4               // LDS window: graphs per block tile

__device__ __forceinline__ float sigf(float z) {
    float e = __expf(-z);
    return __builtin_amdgcn_rcpf(1.0f + e);
}

// ---- K1: fused node-heights + edge/face histograms ------------------------
__global__ __launch_bounds__(256) void prep_kernel(
    const float* __restrict__ x, const float* __restrict__ nw,
    const float* __restrict__ v, const int* __restrict__ ei,
    const int* __restrict__ fi, const int* __restrict__ batch,
    float* __restrict__ nh, int* __restrict__ hist_e, int* __restrict__ hist_f,
    int nhB)
{
    if (blockIdx.x < nhB) {
        int idx = blockIdx.x * 256 + threadIdx.x;
        if (idx < N_NODES * NT) {
            int n = idx >> 5, t = idx & 31;
            float w = nw[n];
            nh[idx] = w * (x[3 * n] * v[t] + x[3 * n + 1] * v[NT + t] + x[3 * n + 2] * v[2 * NT + t]);
        }
        return;
    }
    __shared__ int he[NB], hf[NB];
    if (threadIdx.x < NB) { he[threadIdx.x] = 0; hf[threadIdx.x] = 0; }
    __syncthreads();
    int b = blockIdx.x - nhB;
    int stride = (gridDim.x - nhB) * 256;
    for (int i = b * 256 + threadIdx.x; i < N_EDGES; i += stride)
        atomicAdd(&he[batch[ei[i]]], 1);
    for (int i = b * 256 + threadIdx.x; i < N_FACES; i += stride)
        atomicAdd(&hf[batch[fi[i]]], 1);
    __syncthreads();
    if (threadIdx.x < NB) {
        if (he[threadIdx.x]) atomicAdd(&hist_e[threadIdx.x], he[threadIdx.x]);
        if (hf[threadIdx.x]) atomicAdd(&hist_f[threadIdx.x], hf[threadIdx.x]);
    }
}

// ---- K2: parallel exclusive scan (64 bins x 2 lists) ----------------------
__global__ void scan_kernel(const int* __restrict__ hist_e, const int* __restrict__ hist_f,
                            int* __restrict__ cur_e, int* __restrict__ cur_f) {
    __shared__ int sh[128];
    int tid = threadIdx.x;                 // 128 threads
    sh[tid] = (tid < 64) ? hist_e[tid] : hist_f[tid - 64];
    __syncthreads();
    int which = tid >> 6, lane = tid & 63;
    int s = 0;
    for (int g = 0; g < lane; g++) s += sh[which * 64 + g];
    if (which == 0) cur_e[lane] = s; else cur_f[lane] = s;
}

// ---- K3: counting-sort scatter WITH payload (edges and faces fused) -------
// Writes graph-sorted copies of the simplex data so accum reads pure streams.
__global__ __launch_bounds__(256) void scatter_kernel(
    const int* __restrict__ ei, const float* __restrict__ ew,
    const int* __restrict__ fi, const float* __restrict__ fw,
    const int* __restrict__ batch, int* __restrict__ cur_e, int* __restrict__ cur_f,
    int* __restrict__ gs_e, int* __restrict__ ea, int* __restrict__ eb, float* __restrict__ ews,
    int* __restrict__ gs_f, int* __restrict__ fa, int* __restrict__ fb,
    int* __restrict__ fc, float* __restrict__ fws, int nbE)
{
    __shared__ int cnt[NB], base[NB];
    bool isE = blockIdx.x < nbE;
    int bb = isE ? blockIdx.x : blockIdx.x - nbE;
    int M = isE ? N_EDGES : N_FACES;
    const int* idx0 = isE ? ei : fi;
    int c0 = bb * 1024;
    if (threadIdx.x < NB) cnt[threadIdx.x] = 0;
    __syncthreads();
    int gv[4], iv[4], n = 0;
    #pragma unroll
    for (int k = 0; k < 4; k++) {
        int i = c0 + k * 256 + threadIdx.x;
        if (i < M) { iv[n] = i; gv[n] = batch[idx0[i]]; atomicAdd(&cnt[gv[n]], 1); n++; }
    }
    __syncthreads();
    if (threadIdx.x < NB) {
        base[threadIdx.x] = atomicAdd((isE ? cur_e : cur_f) + threadIdx.x, cnt[threadIdx.x]);
        cnt[threadIdx.x] = 0;
    }
    __syncthreads();
    for (int k = 0; k < n; k++) {
        int g = gv[k], i = iv[k];
        int pos = base[g] + atomicAdd(&cnt[g], 1);
        if (isE) {
            gs_e[pos] = g; ea[pos] = ei[i]; eb[pos] = ei[N_EDGES + i]; ews[pos] = ew[i];
        } else {
            gs_f[pos] = g; fa[pos] = fi[i]; fb[pos] = fi[N_FACES + i];
            fc[pos] = fi[2 * N_FACES + i]; fws[pos] = fw[i];
        }
    }
}

// ---- K4: delta-basis accumulate, LDS-windowed, sorted payload streams -----
__global__ __launch_bounds__(256) void accum_kernel(
    const float* __restrict__ nh, const int* __restrict__ batch,
    const int* __restrict__ gs_e, const int* __restrict__ ea,
    const int* __restrict__ eb, const float* __restrict__ ews,
    const int* __restrict__ gs_f, const int* __restrict__ fa,
    const int* __restrict__ fb, const int* __restrict__ fc,
    const float* __restrict__ fws,
    float* __restrict__ delta, int nbn, int nbe)
{
    __shared__ float tile[WG * NS * NT];   // 16 KB
    int t = threadIdx.x & 31, slot = threadIdx.x >> 5;
    int bid = blockIdx.x;
    int type, i0, i1;
    float sign;
    if (bid < nbn) {
        type = 0; i0 = bid * CH; i1 = min(i0 + CH, N_NODES); sign = 1.0f;
    } else if (bid < nbn + nbe) {
        type = 1; int b = bid - nbn; i0 = b * CH; i1 = min(i0 + CH, N_EDGES); sign = -1.0f;
    } else {
        type = 2; int b = bid - nbn - nbe; i0 = b * CH; i1 = min(i0 + CH, N_FACES); sign = 1.0f;
    }
    int g0 = (type == 0) ? batch[i0] : (type == 1 ? gs_e[i0] : gs_f[i0]);

    for (int k = threadIdx.x; k < WG * NS * NT; k += 256) tile[k] = 0.0f;
    __syncthreads();

    #define EMIT(S, VAL) do { \
        int _o = (S) * NT + t; \
        if (wi < WG) atomicAdd(&tile[wi * (NS * NT) + _o], (VAL)); \
        else atomicAdd(&delta[g * (NS * NT) + _o], sign * (VAL)); } while (0)

    for (int i = i0 + slot; i < i1; i += 8) {
        float h;
        int g;
        if (type == 0) {
            g = batch[i];
            h = nh[i * NT + t];
        } else if (type == 1) {
            g = gs_e[i];
            int na = ea[i], nb2 = eb[i];
            h = fmaxf(nh[na * NT + t], nh[nb2 * NT + t]) * ews[i];
        } else {
            g = gs_f[i];
            int na = fa[i], nb2 = fb[i], nc = fc[i];
            h = fmaxf(fmaxf(nh[na * NT + t], nh[nb2 * NT + t]), nh[nc * NT + t]) * fws[i];
        }
        int wi = g - g0;
        int slo_u = (int)ceilf((h - WIN + 1.0f) * INV_DLIN);
        int shi_u = (int)floorf((h + WIN + 1.0f) * INV_DLIN);
        int slo = slo_u < 0 ? 0 : slo_u;
        int shi = shi_u > (NS - 1) ? (NS - 1) : shi_u;
        float prev = 0.0f;
        for (int s = slo; s <= shi; s++) {
            float vs = sigf(SCALE_C * (-1.0f + s * DLIN - h));
            EMIT(s, vs - prev);
            prev = vs;
        }
        int sstep = shi_u + 1;
        if (sstep <= NS - 1) {
            int sc = sstep < 0 ? 0 : sstep;
            EMIT(sc, 1.0f - prev);
        }
    }
    #undef EMIT

    __syncthreads();
    for (int k = threadIdx.x; k < WG * NS * NT; k += 256) {
        float vv = tile[k];
        if (vv != 0.0f) {
            int wi = k >> 10, cell = k & (NS * NT - 1);
            int g = g0 + wi;
            if (g < NB) atomicAdd(&delta[g * (NS * NT) + cell], sign * vv);
        }
    }
}

// ---- K5: prefix-sum delta over s -> out -----------------------------------
__global__ void finalize_kernel(const float* __restrict__ delta, float* __restrict__ out) {
    int idx = blockIdx.x * blockDim.x + threadIdx.x;   // 0..NB*NT-1, (g,t)
    if (idx >= NB * NT) return;
    int g = idx >> 5, t = idx & 31;
    const float* dg = delta + (g * NS) * NT + t;
    float* og = out + (g * NS) * NT + t;
    float run = 0.0f;
    for (int s = 0; s < NS; s++) {
        run += dg[s * NT];
        og[s * NT] = run;
    }
}

extern "C" void kernel_launch(void* const* d_in, const int* in_sizes, int n_in,
                              void* d_out, int out_size, void* d_ws, size_t ws_size,
                              hipStream_t stream) {
    const float* x     = (const float*)d_in[0];
    const float* nw    = (const float*)d_in[1];
    const int*   ei    = (const int*)d_in[2];
    const float* ew    = (const float*)d_in[3];
    const int*   fi    = (const int*)d_in[4];
    const float* fw    = (const float*)d_in[5];
    const int*   batch = (const int*)d_in[6];
    const float* v     = (const float*)d_in[7];
    const float* lin   = (const float*)d_in[8];
    (void)lin; (void)in_sizes; (void)n_in; (void)ws_size;
    float* out = (float*)d_out;

    char* ws = (char*)d_ws;
    float* delta  = (float*)ws;                         // 256 KB
    int*   hist_e = (int*)(ws + DSZ * 4);               // 64
    int*   hist_f = hist_e + 64;
    int*   cur_e  = hist_e + 128;
    int*   cur_f  = hist_e + 192;
    float* nh     = (float*)(ws + DSZ * 4 + 1024);      // 6.4 MB
    int*   gs_e   = (int*)((char*)nh + (size_t)N_NODES * NT * 4);
    int*   ea     = gs_e + N_EDGES;
    int*   eb     = ea + N_EDGES;
    float* ews    = (float*)(eb + N_EDGES);
    int*   gs_f   = (int*)(ews + N_EDGES);
    int*   fa     = gs_f + N_FACES;
    int*   fb     = fa + N_FACES;
    int*   fc     = fb + N_FACES;
    float* fws    = (float*)(fc + N_FACES);

    hipMemsetAsync(delta, 0, DSZ * 4 + 1024, stream);

    int nhB = (N_NODES * NT + 255) / 256;  // 6250
    prep_kernel<<<nhB + 512, 256, 0, stream>>>(x, nw, v, ei, fi, batch, nh, hist_e, hist_f, nhB);
    scan_kernel<<<1, 128, 0, stream>>>(hist_e, hist_f, cur_e, cur_f);
    int nbE = (N_EDGES + 1023) / 1024, nbF = (N_FACES + 1023) / 1024;
    scatter_kernel<<<nbE + nbF, 256, 0, stream>>>(ei, ew, fi, fw, batch, cur_e, cur_f,
                                                  gs_e, ea, eb, ews, gs_f, fa, fb, fc, fws, nbE);
    int nbn = (N_NODES + CH - 1) / CH;
    int nbe = (N_EDGES + CH - 1) / CH;
    int nbf = (N_FACES + CH - 1) / CH;
    accum_kernel<<<nbn + nbe + nbf, 256, 0, stream>>>(
        nh, batch, gs_e, ea, eb, ews, gs_f, fa, fb, fc, fws, delta, nbn, nbe);
    finalize_kernel<<<(NB * NT + 255) / 256, 256, 0, stream>>>(delta, out);
}